// Round 8
// baseline (400.954 us; speedup 1.0000x reference)
//
#include <hip/hip_runtime.h>
#include <hip/hip_bf16.h>
#include <math.h>

#define N_NODES 50000
#define N_EDGES 800000
#define IN_DIM 128
#define NEG_SLOPE 0.2f
// HEADS*HID = HEADS*OUT = 256 columns in both GEMMs

typedef __attribute__((ext_vector_type(8))) short s16x8;
typedef __attribute__((ext_vector_type(4))) float f32x4;

__device__ inline unsigned short f2bf(float v) {   // RNE fp32->bf16
    unsigned u = __float_as_uint(v);
    unsigned r = (u + 0x7fffu + ((u >> 16) & 1u)) >> 16;
    return (unsigned short)r;
}
__device__ inline float bf2f(unsigned short b) {
    return __uint_as_float(((unsigned)b) << 16);
}
__device__ inline float lrelu(float v) {
    return v >= 0.f ? v : NEG_SLOPE * v;
}

// ---------------- CSR build ----------------

__global__ void zero_int(int* __restrict__ p, int n) {
    int i = blockIdx.x * blockDim.x + threadIdx.x;
    if (i < n) p[i] = 0;
}

__global__ void hist_kernel(const int* __restrict__ dst, int* __restrict__ cnt) {
    int e = blockIdx.x * blockDim.x + threadIdx.x;
    if (e < N_EDGES) atomicAdd(&cnt[dst[e]], 1);
}

// single-block scan, wave-shuffle based (2 barriers per 1024-tile)
__global__ __launch_bounds__(1024) void scan_kernel(const int* __restrict__ cnt,
                                                    int* __restrict__ off, int n) {
    __shared__ int wsum[16];
    __shared__ int carry_s;
    int tid = threadIdx.x, wid = tid >> 6, lane = tid & 63;
    if (tid == 0) carry_s = 0;
    __syncthreads();
    for (int base = 0; base < n; base += 1024) {
        int i = base + tid;
        int v = (i < n) ? cnt[i] : 0;
        int x = v;
#pragma unroll
        for (int s = 1; s < 64; s <<= 1) {
            int t = __shfl_up(x, s, 64);
            if (lane >= s) x += t;
        }
        if (lane == 63) wsum[wid] = x;
        __syncthreads();
        if (wid == 0 && lane < 16) {
            int w = wsum[lane];
#pragma unroll
            for (int s = 1; s < 16; s <<= 1) {
                int t = __shfl_up(w, s, 64);
                if (lane >= s) w += t;
            }
            wsum[lane] = w;   // inclusive scan of wave sums
        }
        __syncthreads();
        int woff = (wid > 0) ? wsum[wid - 1] : 0;
        int incl = carry_s + woff + x;
        if (i < n) off[i] = incl - v;   // exclusive
        __syncthreads();
        if (tid == 1023) carry_s = incl;
        __syncthreads();
    }
    if (threadIdx.x == 0) off[n] = carry_s;
}

__global__ void copy_int(const int* __restrict__ a, int* __restrict__ b, int n) {
    int i = blockIdx.x * blockDim.x + threadIdx.x;
    if (i < n) b[i] = a[i];
}

__global__ void scatter_kernel(const int* __restrict__ src, const int* __restrict__ dst,
                               int* __restrict__ cur, int* __restrict__ csr_src) {
    int e = blockIdx.x * blockDim.x + threadIdx.x;
    if (e < N_EDGES) {
        int d = dst[e];
        int pos = atomicAdd(&cur[d], 1);
        csr_src[pos] = src[e];
    }
}

// ---------------- splits ----------------

// fp32 [n] -> bf16 hi/lo, vectorized 4-wide
__global__ void split_feat(const float* __restrict__ in, unsigned short* __restrict__ hi,
                           unsigned short* __restrict__ lo, int n4) {
    int i = blockIdx.x * blockDim.x + threadIdx.x;
    if (i < n4) {
        float4 v = *reinterpret_cast<const float4*>(&in[i * 4]);
        ushort4 h, l;
        h.x = f2bf(v.x); l.x = f2bf(v.x - bf2f(h.x));
        h.y = f2bf(v.y); l.y = f2bf(v.y - bf2f(h.y));
        h.z = f2bf(v.z); l.z = f2bf(v.z - bf2f(h.z));
        h.w = f2bf(v.w); l.w = f2bf(v.w - bf2f(h.w));
        *reinterpret_cast<ushort4*>(&hi[i * 4]) = h;
        *reinterpret_cast<ushort4*>(&lo[i * 4]) = l;
    }
}

// W [K x 256] fp32 -> Bt hi/lo [256 x K] bf16
template <int K>
__global__ void split_wt(const float* __restrict__ W, unsigned short* __restrict__ Bth,
                         unsigned short* __restrict__ Btl) {
    int k = blockIdx.x;        // 0..K-1
    int c = threadIdx.x;       // 0..255
    float v = W[(size_t)k * 256 + c];
    unsigned short h = f2bf(v);
    Bth[(size_t)c * K + k] = h;
    Btl[(size_t)c * K + k] = f2bf(v - bf2f(h));
}

// ------- LDS-staged MFMA GEMM + fused el/er -------
// Tile: BM=64 rows x BN=256 cols, BK=32. 4 waves; wave h owns head h's 64-col strip
// (mi=4 x ni=4 frags of 16x16x32). Double-buffered 80KB LDS, async global_load_lds.
// LDS set layout (40960 B per buffer):
//   A_hi [kc0..3][row0..63][16B] @ 0      A_lo @ 4096
//   B_hi [kc0..3][col0..255][16B] @ 8192  B_lo @ 24576
// DMA dest is linear in tid per instruction (m104 constraint); frag ds_read_b128
// pattern is 2-way bank aliased only (free, m136).
// frag: lane l holds row/col (l&15), k = (l>>4)*8 + 0..7.
// C/D: col = lane&15, row = (lane>>4)*4 + reg (learn_hip m89).

#define GLDS(gsrc, loff)                                                        \
    __builtin_amdgcn_global_load_lds(                                           \
        (const __attribute__((address_space(1))) unsigned int*)(gsrc),          \
        (__attribute__((address_space(3))) unsigned int*)(lds + (loff)),        \
        16, 0, 0)

template <int K>
__global__ __launch_bounds__(256, 2) void mfma_gemm(const unsigned short* __restrict__ Ahi,
                                                    const unsigned short* __restrict__ Alo,
                                                    const unsigned short* __restrict__ Bth,
                                                    const unsigned short* __restrict__ Btl,
                                                    const float* __restrict__ attl,
                                                    const float* __restrict__ attr,
                                                    unsigned short* __restrict__ Chi,
                                                    float* __restrict__ el,
                                                    float* __restrict__ er,
                                                    int M) {
    __shared__ __align__(16) char lds[81920];
    int tid = threadIdx.x;
    int h = tid >> 6;          // wave = head / 64-col strip
    int lane = tid & 63;
    int rr = lane & 15;
    int g = lane >> 4;
    int row0 = blockIdx.x * 64;

    // staging source addresses (tid-dependent, fixed across k-steps)
    int arow = row0 + (tid & 63);
    if (arow >= M) arow = M - 1;
    int akc = tid >> 6;                       // 0..3
    const unsigned short* asrc_h = Ahi + (size_t)arow * K + akc * 8;
    const unsigned short* asrc_l = Alo + (size_t)arow * K + akc * 8;
    const unsigned short* bsrc_h = Bth + (size_t)tid * K;
    const unsigned short* bsrc_l = Btl + (size_t)tid * K;

    f32x4 acc[4][4] = {};                     // [mi][ni]

    // prologue: stage k-step 0 into buffer 0
    {
        GLDS(asrc_h, tid * 16);
        GLDS(asrc_l, 4096 + tid * 16);
#pragma unroll
        for (int j = 0; j < 4; j++) {
            GLDS(bsrc_h + j * 8, 8192 + j * 4096 + tid * 16);
            GLDS(bsrc_l + j * 8, 24576 + j * 4096 + tid * 16);
        }
    }

    int cur = 0;
    for (int kb = 0; kb < K; kb += 32) {
        __syncthreads();                      // stage for this kb complete
        if (kb + 32 < K) {                    // stage next k-step into other buffer
            int nb = (cur ^ 1) * 40960;
            GLDS(asrc_h + kb + 32, nb + tid * 16);
            GLDS(asrc_l + kb + 32, nb + 4096 + tid * 16);
#pragma unroll
            for (int j = 0; j < 4; j++) {
                GLDS(bsrc_h + kb + 32 + j * 8, nb + 8192 + j * 4096 + tid * 16);
                GLDS(bsrc_l + kb + 32 + j * 8, nb + 24576 + j * 4096 + tid * 16);
            }
        }
        const char* lb = lds + cur * 40960;
        s16x8 ah[4], al[4], bh[4], bl[4];
#pragma unroll
        for (int mi = 0; mi < 4; mi++) {
            int off = g * 1024 + (mi * 16 + rr) * 16;
            ah[mi] = *reinterpret_cast<const s16x8*>(lb + off);
            al[mi] = *reinterpret_cast<const s16x8*>(lb + 4096 + off);
        }
#pragma unroll
        for (int ni = 0; ni < 4; ni++) {
            int off = g * 4096 + (h * 64 + ni * 16 + rr) * 16;
            bh[ni] = *reinterpret_cast<const s16x8*>(lb + 8192 + off);
            bl[ni] = *reinterpret_cast<const s16x8*>(lb + 24576 + off);
        }
#pragma unroll
        for (int mi = 0; mi < 4; mi++) {
#pragma unroll
            for (int ni = 0; ni < 4; ni++) {
                acc[mi][ni] = __builtin_amdgcn_mfma_f32_16x16x32_bf16(ah[mi], bh[ni], acc[mi][ni], 0, 0, 0);
                acc[mi][ni] = __builtin_amdgcn_mfma_f32_16x16x32_bf16(ah[mi], bl[ni], acc[mi][ni], 0, 0, 0);
                acc[mi][ni] = __builtin_amdgcn_mfma_f32_16x16x32_bf16(al[mi], bh[ni], acc[mi][ni], 0, 0, 0);
            }
        }
        cur ^= 1;
    }

    // epilogue: C-write (bf16 hi only) + fused el/er
    float alv[4], arv[4];
#pragma unroll
    for (int ni = 0; ni < 4; ni++) {
        alv[ni] = attl[h * 64 + ni * 16 + rr];
        arv[ni] = attr[h * 64 + ni * 16 + rr];
    }
#pragma unroll
    for (int mi = 0; mi < 4; mi++) {
#pragma unroll
        for (int reg = 0; reg < 4; reg++) {
            int row = row0 + mi * 16 + g * 4 + reg;
            bool ok = row < M;
            float pel = 0.f, per_ = 0.f;
#pragma unroll
            for (int ni = 0; ni < 4; ni++) {
                float v = acc[mi][ni][reg];
                pel += v * alv[ni];
                per_ += v * arv[ni];
                if (ok) Chi[(size_t)row * 256 + h * 64 + ni * 16 + rr] = f2bf(v);
            }
#pragma unroll
            for (int s = 1; s < 16; s <<= 1) {
                pel  += __shfl_xor(pel, s, 64);
                per_ += __shfl_xor(per_, s, 64);
            }
            if (rr == 0 && ok) {
                el[row * 4 + h] = pel;
                er[row * 4 + h] = per_;
            }
        }
    }
}

// ------- aggregation: one wave per node, all 4 heads, batch-8 online softmax -------
// lane l holds features l*4..l*4+3 of the 256-wide row; head h = l>>4.
// LAYER 1: writes elu(res) as bf16 hi/lo (input to GEMM2). LAYER 2: head-mean -> fp32 out.

template <int LAYER>
__global__ __launch_bounds__(256) void agg_kernel(const unsigned short* __restrict__ feat16,
                                                  const float* __restrict__ el,
                                                  const float* __restrict__ er,
                                                  const int* __restrict__ row_off,
                                                  const int* __restrict__ csr_src,
                                                  const float* __restrict__ bias,
                                                  unsigned short* __restrict__ out_hi,
                                                  unsigned short* __restrict__ out_lo,
                                                  float* __restrict__ outf) {
    int n = blockIdx.x * 4 + (threadIdx.x >> 6);   // 12500 blocks * 4 waves = 50000
    int lane = threadIdx.x & 63;
    int h = lane >> 4;
    int js = row_off[n], je = row_off[n + 1];
    float er_nh = er[n * 4 + h];
    float m = -INFINITY, ssum = 0.f;
    float4 acc = make_float4(0.f, 0.f, 0.f, 0.f);
    int j = js;
    for (; j + 7 < je; j += 8) {
        int ss[8]; ushort4 uu[8]; float vv[8];
#pragma unroll
        for (int q = 0; q < 8; q++) ss[q] = csr_src[j + q];
#pragma unroll
        for (int q = 0; q < 8; q++)
            uu[q] = *reinterpret_cast<const ushort4*>(&feat16[(size_t)ss[q] * 256 + lane * 4]);
#pragma unroll
        for (int q = 0; q < 8; q++) vv[q] = lrelu(el[ss[q] * 4 + h] + er_nh);
        float mx = fmaxf(fmaxf(fmaxf(vv[0], vv[1]), fmaxf(vv[2], vv[3])),
                         fmaxf(fmaxf(vv[4], vv[5]), fmaxf(vv[6], vv[7])));
        float mn = fmaxf(m, mx);
        float sc = __expf(m - mn);     // 0 when m == -inf
        float p[8];
#pragma unroll
        for (int q = 0; q < 8; q++) p[q] = __expf(vv[q] - mn);
        float psum = ((p[0] + p[1]) + (p[2] + p[3])) + ((p[4] + p[5]) + (p[6] + p[7]));
        ssum = ssum * sc + psum;
        float ax = 0.f, ay = 0.f, az = 0.f, aw = 0.f;
#pragma unroll
        for (int q = 0; q < 8; q++) {
            ax += p[q] * bf2f(uu[q].x);
            ay += p[q] * bf2f(uu[q].y);
            az += p[q] * bf2f(uu[q].z);
            aw += p[q] * bf2f(uu[q].w);
        }
        acc.x = acc.x * sc + ax;
        acc.y = acc.y * sc + ay;
        acc.z = acc.z * sc + az;
        acc.w = acc.w * sc + aw;
        m = mn;
    }
    for (; j + 3 < je; j += 4) {
        int s0 = csr_src[j], s1 = csr_src[j + 1], s2 = csr_src[j + 2], s3 = csr_src[j + 3];
        ushort4 u0 = *reinterpret_cast<const ushort4*>(&feat16[(size_t)s0 * 256 + lane * 4]);
        ushort4 u1 = *reinterpret_cast<const ushort4*>(&feat16[(size_t)s1 * 256 + lane * 4]);
        ushort4 u2 = *reinterpret_cast<const ushort4*>(&feat16[(size_t)s2 * 256 + lane * 4]);
        ushort4 u3 = *reinterpret_cast<const ushort4*>(&feat16[(size_t)s3 * 256 + lane * 4]);
        float v0 = lrelu(el[s0 * 4 + h] + er_nh);
        float v1 = lrelu(el[s1 * 4 + h] + er_nh);
        float v2 = lrelu(el[s2 * 4 + h] + er_nh);
        float v3 = lrelu(el[s3 * 4 + h] + er_nh);
        float mx = fmaxf(fmaxf(v0, v1), fmaxf(v2, v3));
        float mn = fmaxf(m, mx);
        float sc = __expf(m - mn);
        float p0 = __expf(v0 - mn);
        float p1 = __expf(v1 - mn);
        float p2 = __expf(v2 - mn);
        float p3 = __expf(v3 - mn);
        ssum = ssum * sc + ((p0 + p1) + (p2 + p3));
        acc.x = acc.x * sc + (p0 * bf2f(u0.x) + p1 * bf2f(u1.x)) + (p2 * bf2f(u2.x) + p3 * bf2f(u3.x));
        acc.y = acc.y * sc + (p0 * bf2f(u0.y) + p1 * bf2f(u1.y)) + (p2 * bf2f(u2.y) + p3 * bf2f(u3.y));
        acc.z = acc.z * sc + (p0 * bf2f(u0.z) + p1 * bf2f(u1.z)) + (p2 * bf2f(u2.z) + p3 * bf2f(u3.z));
        acc.w = acc.w * sc + (p0 * bf2f(u0.w) + p1 * bf2f(u1.w)) + (p2 * bf2f(u2.w) + p3 * bf2f(u3.w));
        m = mn;
    }
    for (; j < je; j++) {
        int s = csr_src[j];
        ushort4 u = *reinterpret_cast<const ushort4*>(&feat16[(size_t)s * 256 + lane * 4]);
        float val = lrelu(el[s * 4 + h] + er_nh);
        float mn = fmaxf(m, val);
        float sc = __expf(m - mn);
        float p = __expf(val - mn);
        ssum = ssum * sc + p;
        acc.x = acc.x * sc + p * bf2f(u.x);
        acc.y = acc.y * sc + p * bf2f(u.y);
        acc.z = acc.z * sc + p * bf2f(u.z);
        acc.w = acc.w * sc + p * bf2f(u.w);
        m = mn;
    }
    float inv = 1.f / fmaxf(ssum, 1e-9f);
    // bias index: h*64 + (lane&15)*4 + i == lane*4 + i
    float4 res;
    res.x = acc.x * inv + bias[lane * 4 + 0];
    res.y = acc.y * inv + bias[lane * 4 + 1];
    res.z = acc.z * inv + bias[lane * 4 + 2];
    res.w = acc.w * inv + bias[lane * 4 + 3];
    if (LAYER == 1) {
        res.x = res.x > 0.f ? res.x : __expf(res.x) - 1.f;
        res.y = res.y > 0.f ? res.y : __expf(res.y) - 1.f;
        res.z = res.z > 0.f ? res.z : __expf(res.z) - 1.f;
        res.w = res.w > 0.f ? res.w : __expf(res.w) - 1.f;
        ushort4 hz, lz;
        hz.x = f2bf(res.x); lz.x = f2bf(res.x - bf2f(hz.x));
        hz.y = f2bf(res.y); lz.y = f2bf(res.y - bf2f(hz.y));
        hz.z = f2bf(res.z); lz.z = f2bf(res.z - bf2f(hz.z));
        hz.w = f2bf(res.w); lz.w = f2bf(res.w - bf2f(hz.w));
        *reinterpret_cast<ushort4*>(&out_hi[(size_t)n * 256 + lane * 4]) = hz;
        *reinterpret_cast<ushort4*>(&out_lo[(size_t)n * 256 + lane * 4]) = lz;
    } else {
        // mean over heads: feature f is held by lanes {f>>2, +16, +32, +48}
#pragma unroll
        for (int mask = 16; mask <= 32; mask <<= 1) {
            res.x += __shfl_xor(res.x, mask, 64);
            res.y += __shfl_xor(res.y, mask, 64);
            res.z += __shfl_xor(res.z, mask, 64);
            res.w += __shfl_xor(res.w, mask, 64);
        }
        if (lane < 16) {
            float4 o = make_float4(res.x * 0.25f, res.y * 0.25f, res.z * 0.25f, res.w * 0.25f);
            *reinterpret_cast<float4*>(&outf[(size_t)n * 64 + lane * 4]) = o;
        }
    }
}

// ---------------- launch ----------------

extern "C" void kernel_launch(void* const* d_in, const int* in_sizes, int n_in,
                              void* d_out, int out_size, void* d_ws, size_t ws_size,
                              hipStream_t stream) {
    const float* features = (const float*)d_in[0];
    const int*   src      = (const int*)d_in[1];
    const int*   dst      = (const int*)d_in[2];
    const float* W1       = (const float*)d_in[3];
    const float* al1      = (const float*)d_in[4];
    const float* ar1      = (const float*)d_in[5];
    const float* b1       = (const float*)d_in[6];
    const float* W2       = (const float*)d_in[7];
    const float* al2      = (const float*)d_in[8];
    const float* ar2      = (const float*)d_in[9];
    const float* b2       = (const float*)d_in[10];
    float* out = (float*)d_out;

    char* ws = (char*)d_ws;
    unsigned short* feat16  = (unsigned short*)(ws);             // 25,600,000 B [50000x256]
    unsigned short* h1_hi   = (unsigned short*)(ws + 25600000);  // 25,600,000 B
    unsigned short* h1_lo   = (unsigned short*)(ws + 51200000);  // 25,600,000 B
    unsigned short* fA_hi   = (unsigned short*)(ws + 76800000);  // 12,800,000 B [50000x128]
    unsigned short* fA_lo   = (unsigned short*)(ws + 89600000);  // 12,800,000 B
    unsigned short* Bt1_hi  = (unsigned short*)(ws + 102400000); //     65,536 B
    unsigned short* Bt1_lo  = (unsigned short*)(ws + 102465536); //     65,536 B
    unsigned short* Bt2_hi  = (unsigned short*)(ws + 102531072); //    131,072 B
    unsigned short* Bt2_lo  = (unsigned short*)(ws + 102662144); //    131,072 B
    float*          el      = (float*)(ws + 102793216);          //    800,000 B
    float*          er      = (float*)(ws + 103593216);          //    800,000 B
    int*            row_off = (int*)  (ws + 104393216);          //    200,064 B
    int*            cur     = (int*)  (ws + 104593280);          //    200,000 B
    int*            csr     = (int*)  (ws + 104793280);          //  3,200,000 B  (end ~108 MB)

    // --- CSR build (graph shared by both layers) ---
    zero_int<<<(N_NODES + 255) / 256, 256, 0, stream>>>(cur, N_NODES);
    hist_kernel<<<(N_EDGES + 255) / 256, 256, 0, stream>>>(dst, cur);
    scan_kernel<<<1, 1024, 0, stream>>>(cur, row_off, N_NODES);
    copy_int<<<(N_NODES + 255) / 256, 256, 0, stream>>>(row_off, cur, N_NODES);
    scatter_kernel<<<(N_EDGES + 255) / 256, 256, 0, stream>>>(src, dst, cur, csr);

    // --- splits ---
    split_feat<<<(N_NODES * IN_DIM / 4 + 255) / 256, 256, 0, stream>>>(
        features, fA_hi, fA_lo, N_NODES * IN_DIM / 4);
    split_wt<IN_DIM><<<IN_DIM, 256, 0, stream>>>(W1, Bt1_hi, Bt1_lo);
    split_wt<256><<<256, 256, 0, stream>>>(W2, Bt2_hi, Bt2_lo);

    int gemm_blocks = (N_NODES + 63) / 64;   // 782

    // --- layer 1 ---
    mfma_gemm<IN_DIM><<<gemm_blocks, 256, 0, stream>>>(
        fA_hi, fA_lo, Bt1_hi, Bt1_lo, al1, ar1, feat16, el, er, N_NODES);
    agg_kernel<1><<<12500, 256, 0, stream>>>(feat16, el, er, row_off, csr, b1, h1_hi, h1_lo, nullptr);

    // --- layer 2 ---
    mfma_gemm<256><<<gemm_blocks, 256, 0, stream>>>(
        h1_hi, h1_lo, Bt2_hi, Bt2_lo, al2, ar2, feat16, el, er, N_NODES);
    agg_kernel<2><<<12500, 256, 0, stream>>>(feat16, el, er, row_off, csr, b2, nullptr, nullptr, out);
}